// Round 3
// baseline (193.792 us; speedup 1.0000x reference)
//
#include <hip/hip_runtime.h>

#define B_DIM 4096
#define L_DIM 4096
#define SEGLEN 256
#define NSEG (L_DIM / SEGLEN)   // 16
#define WARM 512                // coupling window for speculative segments (proven exact)
#define CHUNK 64                // time steps per LDS chunk
#define CF4 (CHUNK / 4)         // 16 float4 per row per chunk
#define LSTRIDE 68              // LDS floats per row: 64 + 4 pad (16B-aligned, bank-spread)

// ws layout: float C_acc[4096], float ts_acc[4096], int first_acc[4096]
__global__ __launch_bounds__(256) void init_kernel(float* wsf, int* wsi) {
    int i = blockIdx.x * 256 + threadIdx.x;
    if (i < 2 * B_DIM) wsf[i] = 0.f;
    if (i < B_DIM) wsi[i] = L_DIM;  // min-identity for first-spike
}

// Exact IEEE step (proven absmax 0): q = RN(u/20) via Markstein, compare off
// the dependent chain: u' = sp_prev ? I' : ((u - q) + I')   [reset == I' exactly]
#define LIF_CORE(IIN)                         \
    float q0 = u * cdiv;                      \
    float rr = fmaf(-20.0f, q0, u);           \
    float q  = fmaf(rr, cdiv, q0);            \
    float a  = u - q;                         \
    float b  = a + (IIN);                     \
    u = sp ? (IIN) : b;                       \
    sp = (u >= 1.0f);

#define WARM_STEP(IIN) { LIF_CORE(IIN) }

#define FULL_STEP(IIN, SOUT)                  \
    {                                         \
        LIF_CORE(IIN)                         \
        float sf = sp ? 1.0f : 0.0f;          \
        cnt += sf;                            \
        seen = fmaxf(seen, sf);               \
        accS += cnt;                          \
        accF += seen;                         \
        (SOUT) = sf;                          \
    }

// Raw barrier: LDS handoff needs lgkmcnt(0) only. NO vmcnt drain -> global
// loads/stores stream across phase barriers (T3/T4: counted vmcnt, never 0
// in-loop). sched_barrier(0) fences compiler motion across the barrier.
#define BARRIER_SYNC()                                      \
    asm volatile("s_waitcnt lgkmcnt(0)" ::: "memory");      \
    __builtin_amdgcn_s_barrier();                           \
    __builtin_amdgcn_sched_barrier(0);

// Block = 128 threads: wave 0 computes 64 rows (row-per-lane, one time
// segment); wave 1 stages global->LDS and stores spikes coalesced.
// Double-buffered LDS + depth-2 register pipeline in the producer (T14):
//   phase c: issue loads chunk c+2 -> regs (slot c&1)
//            ds_read spikes(c-1) from buf[(c+1)&1], store to global
//            ds_write chunk c+1 (regs loaded a full phase ago -> vmcnt wait
//            already satisfied; spike stores are youngest, never waited)
//            lgkmcnt(0); s_barrier
// Buffer ownership per phase c (hazard-free, single barrier):
//   compute : buf[c&1]      read input-c, write spikes-c
//   producer: buf[(c+1)&1]  read spikes-(c-1) THEN overwrite with input-(c+1)
//             (in-order LDS pipe, same wave -> read-before-write safe)
__global__ __launch_bounds__(128, 1) void lif_kernel(const float* __restrict__ I,
                                                     float* __restrict__ out,
                                                     float* __restrict__ Cacc,
                                                     float* __restrict__ tsAcc,
                                                     int* __restrict__ firstAcc) {
    __shared__ __align__(16) float lds[2][64 * LSTRIDE];
    const int wid = threadIdx.x >> 6;
    const int lane = threadIdx.x & 63;
    const int seg = blockIdx.x >> 6;
    const int rowBase = (blockIdx.x & 63) * 64;
    const int t0 = seg * SEGLEN;
    const int start = (t0 > WARM) ? (t0 - WARM) : 0;
    const int nwarmCh = (t0 - start) / CHUNK;
    const int nch = nwarmCh + SEGLEN / CHUNK;   // in {4, 8, 12} -> always even

    if (wid == 1) {
        // ---- producer wave ----
        const int srow = lane >> 4, scol = lane & 15;
        const float* gb = I + (size_t)rowBase * L_DIM + start + scol * 4;
        float* ob = out + (size_t)rowBase * L_DIM + t0 + scol * 4;
        float4 Ga[16], Gb[16];

        // prologue: chunk0 -> LDS now; chunk1 loads issued (slack = phase 0)
#pragma unroll
        for (int p = 0; p < 16; ++p)
            Ga[p] = *(const float4*)(gb + (size_t)(4 * p + srow) * L_DIM);
        if (1 < nch) {
            const float* g = gb + CHUNK;
#pragma unroll
            for (int p = 0; p < 16; ++p)
                Gb[p] = *(const float4*)(g + (size_t)(4 * p + srow) * L_DIM);
        }
        {
            float* dst = &lds[0][0];
#pragma unroll
            for (int p = 0; p < 16; ++p)
                *(float4*)&dst[(4 * p + srow) * LSTRIDE + scol * 4] = Ga[p];
        }
        BARRIER_SYNC();

        auto phase = [&](const int c, float4 (&Gld)[16], float4 (&Gwr)[16]) {
            // 1. issue loads for chunk c+2 (earliest -> full-phase slack)
            if (c + 2 < nch) {
                const float* g = gb + (c + 2) * CHUNK;
#pragma unroll
                for (int p = 0; p < 16; ++p)
                    Gld[p] = *(const float4*)(g + (size_t)(4 * p + srow) * L_DIM);
            }
            __builtin_amdgcn_sched_barrier(0);  // keep loads first
            // 2. spikes(c-1): ds_read then coalesced global store (grouped
            //    by 4 to bound register liveness; stores never waited)
            const int cp = c - 1;
            if (cp >= nwarmCh) {
                const float* sb = &lds[cp & 1][0];
                float* og = ob + (size_t)(cp - nwarmCh) * CHUNK;
#pragma unroll
                for (int g4 = 0; g4 < 4; ++g4) {
                    float4 S[4];
#pragma unroll
                    for (int q = 0; q < 4; ++q) {
                        const int r = 4 * (4 * g4 + q) + srow;
                        S[q] = *(const float4*)&sb[r * LSTRIDE + scol * 4];
                    }
#pragma unroll
                    for (int q = 0; q < 4; ++q) {
                        const int r = 4 * (4 * g4 + q) + srow;
                        *(float4*)(og + (size_t)r * L_DIM) = S[q];
                    }
                }
            }
            // 3. ds_write chunk c+1 (loaded last phase -> data already home)
            if (c + 1 < nch) {
                float* dst = &lds[(c + 1) & 1][0];
#pragma unroll
                for (int p = 0; p < 16; ++p)
                    *(float4*)&dst[(4 * p + srow) * LSTRIDE + scol * 4] = Gwr[p];
            }
            BARRIER_SYNC();
        };

        for (int c = 0; c < nch; c += 2) {   // nch even; parity-unrolled so
            phase(c, Ga, Gb);                // reg slots are compile-time
            phase(c + 1, Gb, Ga);            // (rule #20: no runtime index)
        }

        // epilogue: spikes of final chunk (deposited before last barrier)
        {
            const int cp = nch - 1;  // always a main chunk
            const float* sb = &lds[cp & 1][0];
            float* og = ob + (size_t)(cp - nwarmCh) * CHUNK;
#pragma unroll
            for (int p = 0; p < 16; ++p) {
                const int r = 4 * p + srow;
                float4 v = *(const float4*)&sb[r * LSTRIDE + scol * 4];
                *(float4*)(og + (size_t)r * L_DIM) = v;
            }
        }
    } else {
        // ---- compute wave (zero vmem in the loop) ----
        const int row = rowBase + lane;
        float u = 0.f, cnt = 0.f, seen = 0.f, accS = 0.f, accF = 0.f;
        bool sp = false;
        const float cdiv = 0.05f;  // RN(1/20)

        BARRIER_SYNC();  // chunk 0 staged
        for (int c = 0; c < nch; ++c) {
            float* buf = &lds[c & 1][lane * LSTRIDE];
            float4 R[CF4];
#pragma unroll
            for (int j = 0; j < CF4; ++j) R[j] = *(const float4*)(buf + 4 * j);

            if (c < nwarmCh) {
#pragma unroll
                for (int j = 0; j < CF4; ++j) {
                    float4 iv = R[j];
                    WARM_STEP(iv.x) WARM_STEP(iv.y) WARM_STEP(iv.z) WARM_STEP(iv.w)
                }
            } else {
                // overwrite own input buffer with spikes (reads already in R)
#pragma unroll
                for (int j = 0; j < CF4; ++j) {
                    float4 iv = R[j];
                    float4 sv;
                    FULL_STEP(iv.x, sv.x) FULL_STEP(iv.y, sv.y)
                    FULL_STEP(iv.z, sv.z) FULL_STEP(iv.w, sv.w)
                    *(float4*)(buf + 4 * j) = sv;
                }
            }
            BARRIER_SYNC();
        }

        // per-segment partials (all exact integers < 2^24 -> float atomics exact)
        if (cnt > 0.f) {
            const int firstLocal = (int)((float)SEGLEN - accF);
            atomicMin(&firstAcc[row], t0 + firstLocal);
        }
        atomicAdd(&Cacc[row], cnt);
        // sum_t t_global*s = (t0+SEGLEN)*cnt - accS
        atomicAdd(&tsAcc[row], fmaf((float)(t0 + SEGLEN), cnt, -accS));
    }
}

__global__ __launch_bounds__(256) void fin_kernel(const float* __restrict__ Cacc,
                                                  const float* __restrict__ tsAcc,
                                                  const int* __restrict__ firstAcc,
                                                  float* __restrict__ out) {
    int r = blockIdx.x * 256 + threadIdx.x;
    if (r < B_DIM) {
        out[(size_t)B_DIM * L_DIM + r] = (float)firstAcc[r];
        out[(size_t)B_DIM * L_DIM + B_DIM + r] = tsAcc[r] / (Cacc[r] + 1e-6f);
    }
}

extern "C" void kernel_launch(void* const* d_in, const int* in_sizes, int n_in,
                              void* d_out, int out_size, void* d_ws, size_t ws_size,
                              hipStream_t stream) {
    const float* I = (const float*)d_in[0];
    float* out = (float*)d_out;
    float* wsf = (float*)d_ws;
    int* wsi = (int*)((float*)d_ws + 2 * B_DIM);
    (void)in_sizes; (void)n_in; (void)out_size; (void)ws_size;

    init_kernel<<<(2 * B_DIM + 255) / 256, 256, 0, stream>>>(wsf, wsi);
    lif_kernel<<<NSEG * 64, 128, 0, stream>>>(I, out, wsf, wsf + B_DIM, wsi);
    fin_kernel<<<(B_DIM + 255) / 256, 256, 0, stream>>>(wsf, wsf + B_DIM, wsi, out);
}

// Round 4
// 157.461 us; speedup vs baseline: 1.2307x; 1.2307x over previous
//
#include <hip/hip_runtime.h>

#define B_DIM 4096
#define L_DIM 4096
#define SEGLEN 256
#define SUPER 1024              // per-block time span = 4 segments
#define NSUP (L_DIM / SUPER)    // 4
#define WARM 512                // coupling window (proven exact)
#define CHUNK 64                // time steps per LDS chunk
#define CF4 (CHUNK / 4)         // 16 float4 per row per chunk
#define LSTRIDE 68              // LDS floats per row: 64 + 4 pad

// ws layout: float C_acc[4096], float ts_acc[4096], int first_acc[4096]
__global__ __launch_bounds__(256) void init_kernel(float* wsf, int* wsi) {
    int i = blockIdx.x * 256 + threadIdx.x;
    if (i < 2 * B_DIM) wsf[i] = 0.f;
    if (i < B_DIM) wsi[i] = L_DIM;  // min-identity for first-spike
}

// Exact IEEE step (proven absmax 0): q = RN(u/20) via Markstein, compare off
// the dependent chain: u' = sp_prev ? I' : ((u - q) + I')
#define LIF_CORE(IIN)                         \
    float q0 = u * cdiv;                      \
    float rr = fmaf(-20.0f, q0, u);           \
    float q  = fmaf(rr, cdiv, q0);            \
    float a  = u - q;                         \
    float b  = a + (IIN);                     \
    u = sp ? (IIN) : b;                       \
    sp = (u >= 1.0f);

#define WARM_STEP(IIN) { LIF_CORE(IIN) }

#define FULL_STEP(IIN, SOUT)                  \
    {                                         \
        LIF_CORE(IIN)                         \
        float sf = sp ? 1.0f : 0.0f;          \
        cnt += sf;                            \
        seen = fmaxf(seen, sf);               \
        accS += cnt;                          \
        accF += seen;                         \
        (SOUT) = sf;                          \
    }

// LDS handoff needs lgkmcnt(0) only; vmem streams across barriers.
#define BARRIER_SYNC()                                      \
    asm volatile("s_waitcnt lgkmcnt(0)" ::: "memory");      \
    __builtin_amdgcn_s_barrier();                           \
    __builtin_amdgcn_sched_barrier(0);

// Block = 320 threads (5 waves), grid = 256 = 1 block/CU.
// Waves 0..3 each compute one 256-step segment (64 rows, row-per-lane) of a
// shared 1024-step super-segment; their 512-step warm windows OVERLAP the
// neighbors' ranges, so one staged stream [G*1024-512, G*1024+1024) serves
// all four -> warm chunks are loaded ONCE per block (demand loads 184->90MB).
// Wave 4 stages input chunks (depth-2 reg pipeline) and stores spikes
// coalesced from a separate LDS spike-buffer pair (deposit at phase c, store
// at phase c+1). Per-phase s_waitcnt vmcnt(16): stores issued first, 16
// loads for c+2 after -> the wait drains stores (bounds dirty-line lifetime,
// kills round-3's 4x write amplification) while loads keep streaming.
__global__ __launch_bounds__(320, 1) void lif_kernel(const float* __restrict__ I,
                                                     float* __restrict__ out,
                                                     float* __restrict__ Cacc,
                                                     float* __restrict__ tsAcc,
                                                     int* __restrict__ firstAcc) {
    __shared__ __align__(16) float in_lds[2][64 * LSTRIDE];
    __shared__ __align__(16) float sp_lds[2][64 * LSTRIDE];
    const int wid = threadIdx.x >> 6;
    const int lane = threadIdx.x & 63;
    const int G = blockIdx.x >> 6;              // super-segment 0..3
    const int rowBase = (blockIdx.x & 63) * 64;
    const int sbase = G * SUPER;
    const int start = (sbase > WARM) ? (sbase - WARM) : 0;
    const int nch = (sbase + SUPER - start) / CHUNK;   // 16 (G=0) or 24
    const int firstMain = nch - SUPER / CHUNK;         // 0 or 8

    if (wid == 4) {
        // ---- producer wave ----
        const int srow = lane >> 4, scol = lane & 15;
        const float* gb = I + (size_t)rowBase * L_DIM + start + scol * 4;
        float* ob = out + (size_t)rowBase * L_DIM + start + scol * 4;
        float4 Ga[16], Gb[16];

        // prologue: chunk0 -> LDS; chunk1 loads in flight
#pragma unroll
        for (int p = 0; p < 16; ++p)
            Ga[p] = *(const float4*)(gb + (size_t)(4 * p + srow) * L_DIM);
        {
            const float* g1 = gb + CHUNK;
#pragma unroll
            for (int p = 0; p < 16; ++p)
                Gb[p] = *(const float4*)(g1 + (size_t)(4 * p + srow) * L_DIM);
        }
        {
            float* dst = &in_lds[0][0];
#pragma unroll
            for (int p = 0; p < 16; ++p)
                *(float4*)&dst[(4 * p + srow) * LSTRIDE + scol * 4] = Ga[p];
        }
        BARRIER_SYNC();

        auto phase = [&](const int c, float4 (&Gld)[16], float4 (&Gwr)[16]) {
            // 1. spike store of chunk c-1 (oldest vmem this phase)
            const int cp = c - 1;
            if (cp >= firstMain && cp >= 0) {
                const float* sb = &sp_lds[cp & 1][0];
                float* og = ob + (size_t)cp * CHUNK;
#pragma unroll
                for (int g4 = 0; g4 < 4; ++g4) {
                    float4 S[4];
#pragma unroll
                    for (int q = 0; q < 4; ++q) {
                        const int r = 4 * (4 * g4 + q) + srow;
                        S[q] = *(const float4*)&sb[r * LSTRIDE + scol * 4];
                    }
#pragma unroll
                    for (int q = 0; q < 4; ++q) {
                        const int r = 4 * (4 * g4 + q) + srow;
                        *(float4*)(og + (size_t)r * L_DIM) = S[q];
                    }
                }
            }
            __builtin_amdgcn_sched_barrier(0);
            // 2. issue loads for chunk c+2 (youngest -> survive vmcnt(16))
            if (c + 2 < nch) {
                const float* g2 = gb + (c + 2) * CHUNK;
#pragma unroll
                for (int p = 0; p < 16; ++p)
                    Gld[p] = *(const float4*)(g2 + (size_t)(4 * p + srow) * L_DIM);
            }
            __builtin_amdgcn_sched_barrier(0);
            // 3. ds_write chunk c+1 (regs loaded a full phase ago)
            if (c + 1 < nch) {
                float* dst = &in_lds[(c + 1) & 1][0];
#pragma unroll
                for (int p = 0; p < 16; ++p)
                    *(float4*)&dst[(4 * p + srow) * LSTRIDE + scol * 4] = Gwr[p];
            }
            // 4. drain stores, keep the 16 fresh loads in flight
            asm volatile("s_waitcnt vmcnt(16)" ::: "memory");
            BARRIER_SYNC();
        };

        for (int c = 0; c < nch; c += 2) {  // nch even; compile-time reg slots
            phase(c, Ga, Gb);
            phase(c + 1, Gb, Ga);
        }

        // epilogue: spikes of final chunk (deposited before last barrier)
        {
            const int cp = nch - 1;  // always main
            const float* sb = &sp_lds[cp & 1][0];
            float* og = ob + (size_t)cp * CHUNK;
#pragma unroll
            for (int p = 0; p < 16; ++p) {
                const int r = 4 * p + srow;
                float4 v = *(const float4*)&sb[r * LSTRIDE + scol * 4];
                *(float4*)(og + (size_t)r * L_DIM) = v;
            }
        }
    } else {
        // ---- compute wave wid = j in 0..3: segment t0j..t0j+256 ----
        const int row = rowBase + lane;
        const int t0j = sbase + wid * SEGLEN;
        const int wstart = (t0j > WARM) ? (t0j - WARM) : 0;
        const int lo = (wstart - start) / CHUNK;
        const int hi = (t0j + SEGLEN - start) / CHUNK;
        const int mainLo = hi - SEGLEN / CHUNK;
        float u = 0.f, cnt = 0.f, seen = 0.f, accS = 0.f, accF = 0.f;
        bool sp = false;
        const float cdiv = 0.05f;  // RN(1/20)

        BARRIER_SYNC();  // chunk 0 staged
        for (int c = 0; c < nch; ++c) {
            if (c >= lo && c < hi) {  // wave-uniform
                const float* buf = &in_lds[c & 1][lane * LSTRIDE];
                float4 R[CF4];
#pragma unroll
                for (int jj = 0; jj < CF4; ++jj) R[jj] = *(const float4*)(buf + 4 * jj);

                if (c < mainLo) {
#pragma unroll
                    for (int jj = 0; jj < CF4; ++jj) {
                        float4 iv = R[jj];
                        WARM_STEP(iv.x) WARM_STEP(iv.y) WARM_STEP(iv.z) WARM_STEP(iv.w)
                    }
                } else {
                    // main chunk: this wave is the unique owner of sp_lds slot
                    float* sb = &sp_lds[c & 1][lane * LSTRIDE];
#pragma unroll
                    for (int jj = 0; jj < CF4; ++jj) {
                        float4 iv = R[jj];
                        float4 sv;
                        FULL_STEP(iv.x, sv.x) FULL_STEP(iv.y, sv.y)
                        FULL_STEP(iv.z, sv.z) FULL_STEP(iv.w, sv.w)
                        *(float4*)(sb + 4 * jj) = sv;
                    }
                }
            }
            BARRIER_SYNC();
        }

        // per-segment partials (exact integers < 2^24 -> float atomics exact)
        if (cnt > 0.f) {
            const int firstLocal = (int)((float)SEGLEN - accF);
            atomicMin(&firstAcc[row], t0j + firstLocal);
        }
        atomicAdd(&Cacc[row], cnt);
        atomicAdd(&tsAcc[row], fmaf((float)(t0j + SEGLEN), cnt, -accS));
    }
}

__global__ __launch_bounds__(256) void fin_kernel(const float* __restrict__ Cacc,
                                                  const float* __restrict__ tsAcc,
                                                  const int* __restrict__ firstAcc,
                                                  float* __restrict__ out) {
    int r = blockIdx.x * 256 + threadIdx.x;
    if (r < B_DIM) {
        out[(size_t)B_DIM * L_DIM + r] = (float)firstAcc[r];
        out[(size_t)B_DIM * L_DIM + B_DIM + r] = tsAcc[r] / (Cacc[r] + 1e-6f);
    }
}

extern "C" void kernel_launch(void* const* d_in, const int* in_sizes, int n_in,
                              void* d_out, int out_size, void* d_ws, size_t ws_size,
                              hipStream_t stream) {
    const float* I = (const float*)d_in[0];
    float* out = (float*)d_out;
    float* wsf = (float*)d_ws;
    int* wsi = (int*)((float*)d_ws + 2 * B_DIM);
    (void)in_sizes; (void)n_in; (void)out_size; (void)ws_size;

    init_kernel<<<(2 * B_DIM + 255) / 256, 256, 0, stream>>>(wsf, wsi);
    lif_kernel<<<NSUP * 64, 320, 0, stream>>>(I, out, wsf, wsf + B_DIM, wsi);
    fin_kernel<<<(B_DIM + 255) / 256, 256, 0, stream>>>(wsf, wsf + B_DIM, wsi, out);
}